// Round 1
// baseline (48.688 us; speedup 1.0000x reference)
//
#include <hip/hip_runtime.h>
#include <hip/hip_bf16.h>

#define H_EDGES 4096
#define N_NODES 20000
#define FIN 256
#define FOUT 128
#define DEG 32
#define ROWS_TOTAL (H_EDGES + N_NODES)  // 24096

// ---------------- K1: qk = [hedge; node] @ Wq  (fp32, vector ALU) ----------
// M=24096, N=128 (full), K=256 in chunks of 64. 256 threads/block.
// Thread tile 8 rows x 4 cols -> 32 acc. a_lds stored transposed [k][row]
// with stride 68 (keeps 16B alignment for float4 reads, spreads banks).
#define MT 64
#define KT 64
#define AS 68

__global__ __launch_bounds__(256)
void k1_gemm(const float* __restrict__ hedge, const float* __restrict__ node,
             const float* __restrict__ Wq, float* __restrict__ qk) {
    __shared__ float a_lds[KT * AS];     // [k][r]
    __shared__ float b_lds[KT * FOUT];   // [k][c]
    const int t  = threadIdx.x;
    const int tx = t & 31;               // col quad index
    const int ty = t >> 5;               // row octet index
    const int row_base = blockIdx.x * MT;

    float acc[8][4];
    #pragma unroll
    for (int i = 0; i < 8; ++i)
        #pragma unroll
        for (int j = 0; j < 4; ++j) acc[i][j] = 0.f;

    const int r_ld  = t >> 2;            // 0..63: A-staging row
    const int kq_ld = (t & 3) * 4;       // A-staging k-quad base

    for (int kk = 0; kk < FIN; kk += KT) {
        // stage A (transpose at write; 2-way bank alias only -> free)
        {
            const int row = row_base + r_ld;
            const float* src = nullptr;
            if (row < H_EDGES) src = hedge + (size_t)row * FIN;
            else if (row < ROWS_TOTAL) src = node + (size_t)(row - H_EDGES) * FIN;
            #pragma unroll
            for (int j = 0; j < 4; ++j) {
                const int k0 = kq_ld + 16 * j;
                float4 v = src ? *(const float4*)(src + kk + k0)
                               : make_float4(0.f, 0.f, 0.f, 0.f);
                a_lds[(k0 + 0) * AS + r_ld] = v.x;
                a_lds[(k0 + 1) * AS + r_ld] = v.y;
                a_lds[(k0 + 2) * AS + r_ld] = v.z;
                a_lds[(k0 + 3) * AS + r_ld] = v.w;
            }
        }
        // stage B: 64 x 128 floats, 8 float4 per thread, fully coalesced
        #pragma unroll
        for (int j = 0; j < 8; ++j) {
            const int idx4 = t + 256 * j;
            const int k  = idx4 >> 5;
            const int c4 = (idx4 & 31) * 4;
            *(float4*)&b_lds[k * FOUT + c4] =
                *(const float4*)(Wq + (size_t)(kk + k) * FOUT + c4);
        }
        __syncthreads();
        #pragma unroll 4
        for (int k = 0; k < KT; ++k) {
            float4 a0 = *(const float4*)&a_lds[k * AS + ty * 8];
            float4 a1 = *(const float4*)&a_lds[k * AS + ty * 8 + 4];
            float4 b  = *(const float4*)&b_lds[k * FOUT + tx * 4];
            float av[8] = {a0.x, a0.y, a0.z, a0.w, a1.x, a1.y, a1.z, a1.w};
            float bv[4] = {b.x, b.y, b.z, b.w};
            #pragma unroll
            for (int i = 0; i < 8; ++i)
                #pragma unroll
                for (int j = 0; j < 4; ++j)
                    acc[i][j] = fmaf(av[i], bv[j], acc[i][j]);
        }
        __syncthreads();
    }
    #pragma unroll
    for (int i = 0; i < 8; ++i) {
        const int row = row_base + ty * 8 + i;
        if (row < ROWS_TOTAL) {
            float4 v = make_float4(acc[i][0], acc[i][1], acc[i][2], acc[i][3]);
            *(float4*)&qk[(size_t)row * FOUT + tx * 4] = v;
        }
    }
}

// ---------------- K2: per-hyperedge gather + softmax + aggregate -----------
// One block (256 thr) per edge. Dedup duplicate member cols (reference's
// boolean-mask semantics: a node repeated in a hyperedge counts ONCE).
__global__ __launch_bounds__(256)
void k2_attn(const float* __restrict__ qk, const int* __restrict__ col_idx,
             float* __restrict__ out_t) {
    const int h = blockIdx.x;
    const int t = threadIdx.x;
    __shared__ float q_l[FOUT];
    __shared__ float k_l[DEG][FOUT + 4];   // stride 132: bank spread, 16B-aligned rows
    __shared__ float s_l[DEG];
    __shared__ float w_l[DEG];
    __shared__ int   c_l[DEG];

    const float* qmat = qk;
    const float* kmat = qk + (size_t)H_EDGES * FOUT;

    if (t < DEG) c_l[t] = col_idx[(size_t)h * DEG + t];
    if (t < 32)
        *(float4*)&q_l[t * 4] = *(const float4*)&qmat[(size_t)h * FOUT + t * 4];
    __syncthreads();

    // gather 32 k-rows -> LDS (512B contiguous per row, coalesced)
    {
        const int m0 = t >> 5;
        const int c4 = (t & 31) * 4;
        #pragma unroll
        for (int j = 0; j < 4; ++j) {
            const int m = m0 + 8 * j;
            *(float4*)&k_l[m][c4] =
                *(const float4*)&kmat[(size_t)c_l[m] * FOUT + c4];
        }
    }
    __syncthreads();

    // scores: 8 lanes per member, 16 elements each, shfl-reduce within octet
    {
        const int m  = t >> 3;
        const int i0 = (t & 7) * 16;
        float p = 0.f;
        #pragma unroll
        for (int j = 0; j < 4; ++j) {
            float4 a = *(const float4*)&q_l[i0 + j * 4];
            float4 b = *(const float4*)&k_l[m][i0 + j * 4];
            p = fmaf(a.x, b.x, p); p = fmaf(a.y, b.y, p);
            p = fmaf(a.z, b.z, p); p = fmaf(a.w, b.w, p);
        }
        p += __shfl_xor(p, 1);
        p += __shfl_xor(p, 2);
        p += __shfl_xor(p, 4);
        if ((t & 7) == 0) s_l[m] = p * 0.08838834764831845f;  // 1/sqrt(128)
    }
    __syncthreads();

    // dedup + softmax on lanes 0..31 of wave 0
    if (t < DEG) {
        const int c = c_l[t];
        bool valid = true;
        for (int j = 0; j < t; ++j)
            if (c_l[j] == c) valid = false;
        float s = valid ? s_l[t] : -INFINITY;
        float mx = s;
        #pragma unroll
        for (int d = 1; d < 32; d <<= 1) mx = fmaxf(mx, __shfl_xor(mx, d));
        float e = valid ? expf(s - mx) : 0.f;
        float sum = e;
        #pragma unroll
        for (int d = 1; d < 32; d <<= 1) sum += __shfl_xor(sum, d);
        w_l[t] = e / sum;
    }
    __syncthreads();

    // aggregate: out_t[h][f] = sum_m w[m] * k[m][f]  (coalesced store)
    if (t < FOUT) {
        float acc = 0.f;
        #pragma unroll
        for (int m = 0; m < DEG; ++m) acc = fmaf(w_l[m], k_l[m][t], acc);
        out_t[(size_t)h * FOUT + t] = acc;
    }
}

// ---------------- K3: transpose [H][FOUT] -> [FOUT][H] ---------------------
__global__ __launch_bounds__(256)
void k3_transpose(const float* __restrict__ out_t, float* __restrict__ out) {
    __shared__ float tile[32][33];
    const int tx = threadIdx.x;   // 0..31
    const int ty = threadIdx.y;   // 0..7
    const int h0 = blockIdx.x * 32;
    const int f0 = blockIdx.y * 32;
    #pragma unroll
    for (int j = 0; j < 4; ++j) {
        const int h = h0 + ty + j * 8;
        tile[ty + j * 8][tx] = out_t[(size_t)h * FOUT + f0 + tx];
    }
    __syncthreads();
    #pragma unroll
    for (int j = 0; j < 4; ++j) {
        const int f = f0 + ty + j * 8;
        out[(size_t)f * H_EDGES + h0 + tx] = tile[tx][ty + j * 8];
    }
}

extern "C" void kernel_launch(void* const* d_in, const int* in_sizes, int n_in,
                              void* d_out, int out_size, void* d_ws, size_t ws_size,
                              hipStream_t stream) {
    const float* hedge = (const float*)d_in[0];
    const float* node  = (const float*)d_in[1];
    const float* Wq    = (const float*)d_in[2];
    // d_in[3] = row_idx: by construction row_idx[e] == e / DEG -> unused
    const int* col_idx = (const int*)d_in[4];
    float* out = (float*)d_out;

    float* qk    = (float*)d_ws;                       // [24096][128] fp32
    float* out_t = qk + (size_t)ROWS_TOTAL * FOUT;     // [4096][128] fp32

    k1_gemm<<<(ROWS_TOTAL + MT - 1) / MT, 256, 0, stream>>>(hedge, node, Wq, qk);
    k2_attn<<<H_EDGES, 256, 0, stream>>>(qk, col_idx, out_t);
    k3_transpose<<<dim3(H_EDGES / 32, FOUT / 32), dim3(32, 8), 0, stream>>>(out_t, out);
}

// Round 2
// 37.558 us; speedup vs baseline: 1.2964x; 1.2964x over previous
//
#include <hip/hip_runtime.h>
#include <hip/hip_bf16.h>
#include <stdint.h>

#define H_EDGES 4096
#define N_NODES 20000
#define FIN 256
#define FOUT 128
#define DEG 32
#define ROWS_TOTAL (H_EDGES + N_NODES)  // 24096

typedef float f32x4 __attribute__((ext_vector_type(4)));
typedef short s16x8 __attribute__((ext_vector_type(8)));
typedef unsigned short u16;

__device__ __forceinline__ u16 f2bf(float f) {
    unsigned u = __builtin_bit_cast(unsigned, f);
    return (u16)((u + 0x7FFFu + ((u >> 16) & 1u)) >> 16);   // RNE
}
__device__ __forceinline__ float bf2f(u16 h) {
    unsigned u = ((unsigned)h) << 16;
    return __builtin_bit_cast(float, u);
}

// ---------- k0: Wq fp32 [256][128] -> Bt bf16 [col][k], XOR-pre-swizzled ----
// Bt slot layout: 16B slot s within row c holds B[k=s*8 .. s*8+7][c];
// stored at physical slot (s ^ (c&7)) so K1 LDS copies stay linear while
// fragment reads are bank-conflict-free.
__global__ __launch_bounds__(256)
void k0_prep(const float* __restrict__ Wq, u16* __restrict__ bt) {
    const int s = blockIdx.x * 256 + threadIdx.x;   // 0..4095
    const int c = s >> 5, kslot = s & 31;
    const int k0 = kslot * 8;
    s16x8 v;
    #pragma unroll
    for (int j = 0; j < 8; ++j) v[j] = (short)f2bf(Wq[(size_t)(k0 + j) * FOUT + c]);
    *(s16x8*)(bt + (size_t)(c * 32 + (kslot ^ (c & 7))) * 8) = v;
}

// ---------- k1: qk = [hedge; node] @ Wq via bf16 MFMA -----------------------
// 189 blocks x 256 thr (4 waves). BM=128 rows/block, 32 rows/wave (2 row-frags).
// A: global->reg direct (fp32 read once, cvt to bf16). B: 64KB LDS, staged once.
#define BM 128
__global__ __launch_bounds__(256)
void k1_gemm(const float* __restrict__ hedge, const float* __restrict__ node,
             const u16* __restrict__ bt, u16* __restrict__ qk) {
    __shared__ u16 blds[FOUT * FIN];   // 64KB
    const int t = threadIdx.x;
    {
        const s16x8* src = (const s16x8*)bt;
        s16x8* dst = (s16x8*)blds;
        #pragma unroll
        for (int j = 0; j < 16; ++j) { const int s = t + 256 * j; dst[s] = src[s]; }
    }
    const int w  = t >> 6, l = t & 63;
    const int lr = l & 15;        // fragment row/col lane
    const int lp = l >> 4;        // k-part (0..3)
    const long rb   = (long)blockIdx.x * BM + w * 32;
    const long row0 = rb + lr;
    const long row1 = row0 + 16;
    const float* pa0 = row0 < H_EDGES ? hedge + row0 * FIN
                     : (row0 < ROWS_TOTAL ? node + (row0 - H_EDGES) * FIN : nullptr);
    const float* pa1 = row1 < H_EDGES ? hedge + row1 * FIN
                     : (row1 < ROWS_TOTAL ? node + (row1 - H_EDGES) * FIN : nullptr);

    f32x4 acc[2][8];
    #pragma unroll
    for (int i = 0; i < 2; ++i)
        #pragma unroll
        for (int j = 0; j < 8; ++j) acc[i][j] = (f32x4){0.f, 0.f, 0.f, 0.f};

    __syncthreads();

    #pragma unroll
    for (int ks = 0; ks < 8; ++ks) {
        const int koff = ks * 32 + lp * 8;   // float offset within row
        s16x8 a0, a1;
        if (pa0) {
            f32x4 u = *(const f32x4*)(pa0 + koff);
            f32x4 v = *(const f32x4*)(pa0 + koff + 4);
            #pragma unroll
            for (int j = 0; j < 4; ++j) { a0[j] = (short)f2bf(u[j]); a0[j+4] = (short)f2bf(v[j]); }
        } else {
            #pragma unroll
            for (int j = 0; j < 8; ++j) a0[j] = 0;
        }
        if (pa1) {
            f32x4 u = *(const f32x4*)(pa1 + koff);
            f32x4 v = *(const f32x4*)(pa1 + koff + 4);
            #pragma unroll
            for (int j = 0; j < 4; ++j) { a1[j] = (short)f2bf(u[j]); a1[j+4] = (short)f2bf(v[j]); }
        } else {
            #pragma unroll
            for (int j = 0; j < 8; ++j) a1[j] = 0;
        }
        #pragma unroll
        for (int cf = 0; cf < 8; ++cf) {
            const int col  = cf * 16 + lr;
            const int phys = col * 32 + ((ks * 4 + lp) ^ (col & 7));
            s16x8 b = *(const s16x8*)(blds + (size_t)phys * 8);
            acc[0][cf] = __builtin_amdgcn_mfma_f32_16x16x32_bf16(a0, b, acc[0][cf], 0, 0, 0);
            acc[1][cf] = __builtin_amdgcn_mfma_f32_16x16x32_bf16(a1, b, acc[1][cf], 0, 0, 0);
        }
    }

    // epilogue: D lane map row=(l>>4)*4+i, col=l&15 within each 16x16 frag
    #pragma unroll
    for (int fr = 0; fr < 2; ++fr) {
        #pragma unroll
        for (int i = 0; i < 4; ++i) {
            const long row = rb + fr * 16 + lp * 4 + i;
            if (row < ROWS_TOTAL) {
                #pragma unroll
                for (int cf = 0; cf < 8; ++cf)
                    qk[(size_t)row * FOUT + cf * 16 + lr] = f2bf(acc[fr][cf][i]);
            }
        }
    }
}

// ---------- k2: per-hyperedge gather + dedup softmax + aggregate ------------
__global__ __launch_bounds__(256)
void k2_attn(const u16* __restrict__ qk, const int* __restrict__ col_idx,
             float* __restrict__ out_t) {
    const int h = blockIdx.x;
    const int t = threadIdx.x;
    __shared__ float q_l[FOUT];
    __shared__ u16  k_l[DEG][136];   // 272B row stride: 16B-aligned, bank-spread
    __shared__ float s_l[DEG];
    __shared__ float w_l[DEG];
    __shared__ int   c_l[DEG];

    const u16* kmat = qk + (size_t)H_EDGES * FOUT;

    if (t < DEG) c_l[t] = col_idx[(size_t)h * DEG + t];
    if (t < 16) {
        s16x8 v = *(const s16x8*)(qk + (size_t)h * FOUT + t * 8);
        #pragma unroll
        for (int j = 0; j < 8; ++j) q_l[t * 8 + j] = bf2f((u16)v[j]);
    }
    __syncthreads();

    // gather 32 rows x 256B bf16
    #pragma unroll
    for (int j = 0; j < 2; ++j) {
        const int s = t + 256 * j;
        const int m = s >> 4, sl = s & 15;
        s16x8 v = *(const s16x8*)(kmat + (size_t)c_l[m] * FOUT + sl * 8);
        *(s16x8*)&k_l[m][sl * 8] = v;
    }
    __syncthreads();

    // scores: 8 lanes/member, 16 elems each
    {
        const int m  = t >> 3;
        const int i0 = (t & 7) * 16;
        float p = 0.f;
        #pragma unroll
        for (int half = 0; half < 2; ++half) {
            s16x8 kv = *(const s16x8*)&k_l[m][i0 + half * 8];
            #pragma unroll
            for (int j = 0; j < 8; ++j)
                p = fmaf(q_l[i0 + half * 8 + j], bf2f((u16)kv[j]), p);
        }
        p += __shfl_xor(p, 1);
        p += __shfl_xor(p, 2);
        p += __shfl_xor(p, 4);
        if ((t & 7) == 0) s_l[m] = p * 0.08838834764831845f;  // 1/sqrt(128)
    }
    __syncthreads();

    // dedup + softmax (lanes 0..31)
    if (t < DEG) {
        const int c = c_l[t];
        bool valid = true;
        for (int j = 0; j < t; ++j)
            if (c_l[j] == c) valid = false;
        float s = valid ? s_l[t] : -INFINITY;
        float mx = s;
        #pragma unroll
        for (int d = 1; d < 32; d <<= 1) mx = fmaxf(mx, __shfl_xor(mx, d));
        float e = valid ? expf(s - mx) : 0.f;
        float sum = e;
        #pragma unroll
        for (int d = 1; d < 32; d <<= 1) sum += __shfl_xor(sum, d);
        w_l[t] = e / sum;
    }
    __syncthreads();

    if (t < FOUT) {
        float acc = 0.f;
        #pragma unroll
        for (int m = 0; m < DEG; ++m) acc = fmaf(w_l[m], bf2f(k_l[m][t]), acc);
        out_t[(size_t)h * FOUT + t] = acc;
    }
}

// ---------- k3: transpose [H][FOUT] fp32 -> [FOUT][H] -----------------------
__global__ __launch_bounds__(256)
void k3_transpose(const float* __restrict__ out_t, float* __restrict__ out) {
    __shared__ float tile[32][33];
    const int tx = threadIdx.x;   // 0..31
    const int ty = threadIdx.y;   // 0..7
    const int h0 = blockIdx.x * 32;
    const int f0 = blockIdx.y * 32;
    #pragma unroll
    for (int j = 0; j < 4; ++j) {
        const int h = h0 + ty + j * 8;
        tile[ty + j * 8][tx] = out_t[(size_t)h * FOUT + f0 + tx];
    }
    __syncthreads();
    #pragma unroll
    for (int j = 0; j < 4; ++j) {
        const int f = f0 + ty + j * 8;
        out[(size_t)f * H_EDGES + h0 + tx] = tile[tx][ty + j * 8];
    }
}

extern "C" void kernel_launch(void* const* d_in, const int* in_sizes, int n_in,
                              void* d_out, int out_size, void* d_ws, size_t ws_size,
                              hipStream_t stream) {
    const float* hedge = (const float*)d_in[0];
    const float* node  = (const float*)d_in[1];
    const float* Wq    = (const float*)d_in[2];
    const int* col_idx = (const int*)d_in[4];   // row_idx (d_in[3]) is e/DEG by construction
    float* out = (float*)d_out;

    u16*   qk    = (u16*)d_ws;                                    // 24096*128 bf16
    float* out_t = (float*)((char*)d_ws + (size_t)ROWS_TOTAL * FOUT * 2);      // 2MB fp32
    u16*   bt    = (u16*)((char*)out_t + (size_t)H_EDGES * FOUT * 4);          // 64KB bf16

    k0_prep<<<16, 256, 0, stream>>>(Wq, bt);
    k1_gemm<<<(ROWS_TOTAL + BM - 1) / BM, 256, 0, stream>>>(hedge, node, bt, qk);
    k2_attn<<<H_EDGES, 256, 0, stream>>>(qk, col_idx, out_t);
    k3_transpose<<<dim3(H_EDGES / 32, FOUT / 32), dim3(32, 8), 0, stream>>>(out_t, out);
}